// Round 5
// baseline (292.539 us; speedup 1.0000x reference)
//
#include <hip/hip_runtime.h>
#include <math.h>

#define L_SEQ 4096
#define D_DIM 768
#define C3    2304
#define TAPS  32

typedef __attribute__((ext_vector_type(8))) short bf16x8;
typedef __attribute__((ext_vector_type(4))) float f32x4;

__device__ __forceinline__ unsigned short f2bf(float x) {
  union { float f; unsigned u; } v; v.f = x;
  unsigned r = v.u + 0x7FFF + ((v.u >> 16) & 1);
  return (unsigned short)(r >> 16);
}
__device__ __forceinline__ float bf2f(unsigned short u) {
  union { unsigned u; float f; } v; v.u = ((unsigned)u) << 16; return v.f;
}
__device__ __forceinline__ void gld_lds16(const void* g, void* l) {
  __builtin_amdgcn_global_load_lds((const __attribute__((address_space(1))) void*)g,
                                   (__attribute__((address_space(3))) void*)l, 16, 0, 0);
}
// per-wave LDS fence (fbuf is wave-private scratch: no cross-wave barrier needed;
// DS ops are wave-FIFO, lgkmcnt(0)+sched_barrier prevents compiler reordering — rule #18)
__device__ __forceinline__ void lds_fence() {
  asm volatile("s_waitcnt lgkmcnt(0)" ::: "memory");
  __builtin_amdgcn_sched_barrier(0);
}

// ---------------- prep: fused filt + cvt + wtrans (7 -> 5 launches) ----------------
// blocks [0,12288): cvt u fp32->bf16 ; [12288,14592): wtrans ; [14592,14784): filt
__global__ __launch_bounds__(256) void prep_kernel(const float* __restrict__ u,
                                                   unsigned short* __restrict__ ubf,
                                                   const float* __restrict__ W_in,
                                                   unsigned short* __restrict__ W_inT,
                                                   const float* __restrict__ W_out,
                                                   unsigned short* __restrict__ W_outT,
                                                   const float* __restrict__ W1,
                                                   const float* __restrict__ b1,
                                                   const float* __restrict__ W2,
                                                   const float* __restrict__ b2,
                                                   const float* __restrict__ f_decay,
                                                   float* __restrict__ g_tab) {
  __shared__ float sh[2048];
  const int bid = blockIdx.x;
  const int tid = threadIdx.x;
  if (bid < 12288) {
    // ---- cvt ----
    int idx = (bid * 256 + tid) * 4;
    float4 v = *(const float4*)&u[idx];
    ushort4 o;
    o.x = f2bf(v.x); o.y = f2bf(v.y); o.z = f2bf(v.z); o.w = f2bf(v.w);
    *(ushort4*)&ubf[idx] = o;
  } else if (bid < 14592) {
    // ---- wtrans: fp32 [768][C] -> bf16 [C][768] ----
    float (*t)[33] = (float(*)[33])sh;
    int id = bid - 12288;
    const int z = (id >= 1728) ? 1 : 0;
    if (z) id -= 1728;
    const int nx = z ? 24 : 72;
    const int bx = id % nx, by = id / nx;
    const float* src = z ? W_out : W_in;
    unsigned short* dst = z ? W_outT : W_inT;
    const int C = z ? 768 : 2304;
    const int c0 = bx * 32, r0 = by * 32;
    const int tx = tid & 31, ty = tid >> 5;
    #pragma unroll
    for (int rr = 0; rr < 4; ++rr)
      t[ty + rr * 8][tx] = src[(long)(r0 + ty + rr * 8) * C + c0 + tx];
    __syncthreads();
    #pragma unroll
    for (int rr = 0; rr < 4; ++rr)
      dst[(long)(c0 + ty + rr * 8) * 768 + r0 + tx] = f2bf(t[tx][ty + rr * 8]);
  } else {
    // ---- filt: g_tab[c2][t] for t<32 ----
    float* phi_s = sh;
    const int fb = bid - 14592;          // [0,192)
    #pragma unroll
    for (int it = 0; it < 8; ++it) {
      int idx = tid + it * 256;
      int t = idx >> 6, f = idx & 63;
      float tt = (float)t / 4095.0f;
      float s = b1[f];
      #pragma unroll
      for (int e = 0; e < 33; ++e)
        s += sinf(tt * (float)e * 10.0f) * W1[e * 64 + f];
      phi_s[idx] = sinf(10.0f * s);
    }
    __syncthreads();
    int idx = fb * 256 + tid;            // 1536*32
    int c2 = idx >> 5, t = idx & 31;
    float acc = b2[c2];
    #pragma unroll 8
    for (int f = 0; f < 64; ++f)
      acc += phi_s[t * 64 + f] * W2[f * 1536 + c2];
    float r = expf(f_decay[c2]);
    g_tab[idx] = acc * expf(-r * (float)t * (4096.0f / 4095.0f));
  }
}

// ---------------- GEMM1: 256x128 tile, BK=32, ring-3 24KB (2 blk = 16 waves/CU) ----------------
// r3-proven config (77.5us). T2 chunk swizzle (conflicts 5.3M->0.59M verified), counted
// vmcnt(3), setprio. Epilogue: per-wave fbuf -> lds_fence instead of __syncthreads.
__device__ __forceinline__ void g1_vmwait(int VM) {
  if (VM == 3)      asm volatile("s_waitcnt vmcnt(3)" ::: "memory");
  else if (VM == 0) asm volatile("s_waitcnt vmcnt(0)" ::: "memory");
}

template<bool STG, int VM>
__device__ __forceinline__ void g1_step(int scur, int sstg, int kt, char* smemc, int tid,
                                        int wmRow, int wn64, int fm, int csel,
                                        const unsigned short* aP, const unsigned short* bP,
                                        f32x4 (&acc)[4][4]) {
  const unsigned short* As = (const unsigned short*)(smemc + scur * 24576);
  const unsigned short* Bs = (const unsigned short*)(smemc + scur * 24576 + 16384);
  bf16x8 af[4], bfr[4];
  #pragma unroll
  for (int i = 0; i < 4; ++i) af[i]  = *(const bf16x8*)&As[(wmRow + i * 16 + fm) * 32 + csel];
  #pragma unroll
  for (int jj = 0; jj < 4; ++jj) bfr[jj] = *(const bf16x8*)&Bs[(wn64 + jj * 16 + fm) * 32 + csel];
  if (STG) {
    const unsigned short* ap = aP + (kt + 2) * 32;
    const unsigned short* bp = bP + (kt + 2) * 32;
    char* d = smemc + sstg * 24576 + tid * 16;
    gld_lds16(ap,         d);
    gld_lds16(ap + 98304, d + 8192);   // A rows 128..255
    gld_lds16(bp,         d + 16384);  // B rows 0..127
  }
  asm volatile("" ::: "memory");
  __builtin_amdgcn_s_barrier();
  __builtin_amdgcn_s_setprio(1);
  __builtin_amdgcn_sched_barrier(0);
  #pragma unroll
  for (int i = 0; i < 4; ++i)
    #pragma unroll
    for (int jj = 0; jj < 4; ++jj)
      acc[i][jj] = __builtin_amdgcn_mfma_f32_16x16x32_bf16(af[i], bfr[jj], acc[i][jj], 0, 0, 0);
  __builtin_amdgcn_sched_barrier(0);
  __builtin_amdgcn_s_setprio(0);
  g1_vmwait(VM);
  asm volatile("" ::: "memory");
  __builtin_amdgcn_s_barrier();
}

__global__ __launch_bounds__(512, 4) void gemm1_2ph(const unsigned short* __restrict__ A,
                                                    const unsigned short* __restrict__ Bt,
                                                    const float* __restrict__ bias,
                                                    unsigned short* __restrict__ proj) {
  extern __shared__ char smemc[];          // 73728 B dynamic (3 x 24576)
  const int tid = threadIdx.x;
  const int w = tid >> 6, lane = tid & 63;
  const int id = blockIdx.x;
  const int x8 = id & 7, jb = id >> 3;            // 1152 blocks, bijective XCD swizzle
  const int mt = x8 * 8 + jb / 18, nt = jb % 18;
  const int m0 = mt * 256, n0 = nt * 128;
  const int wmRow = (w & 3) * 64, wn64 = (w >> 2) * 64;
  const int fm = lane & 15;
  const int csel = (((lane >> 4) ^ ((fm >> 1) & 3)) << 3);
  const int q_src = ((tid & 3) ^ ((tid >> 3) & 3)) * 8;
  const unsigned short* aP = A  + (size_t)(m0 + (tid >> 2)) * 768 + q_src;
  const unsigned short* bP = Bt + (size_t)(n0 + (tid >> 2)) * 768 + q_src;
  f32x4 acc[4][4] = {};

  #pragma unroll
  for (int kt = 0; kt < 2; ++kt) {
    char* d = smemc + kt * 24576 + tid * 16;
    const unsigned short* ap = aP + kt * 32;
    const unsigned short* bp = bP + kt * 32;
    gld_lds16(ap,         d);
    gld_lds16(ap + 98304, d + 8192);
    gld_lds16(bp,         d + 16384);
  }
  asm volatile("s_waitcnt vmcnt(3)" ::: "memory");
  asm volatile("" ::: "memory");
  __builtin_amdgcn_s_barrier();

  int scur = 0;
  #pragma unroll 1
  for (int kt = 0; kt < 22; ++kt) {
    int sstg = scur + 2; if (sstg >= 3) sstg -= 3;
    g1_step<true, 3>(scur, sstg, kt, smemc, tid, wmRow, wn64, fm, csel, aP, bP, acc);
    scur = (scur == 2) ? 0 : scur + 1;
  }
  {
    int sstg = scur + 2; if (sstg >= 3) sstg -= 3;
    g1_step<false, 0>(scur, sstg, 22, smemc, tid, wmRow, wn64, fm, csel, aP, bP, acc);
    scur = (scur == 2) ? 0 : scur + 1;
  }
  g1_step<false, -1>(scur, 0, 23, smemc, tid, wmRow, wn64, fm, csel, aP, bP, acc);

  // epilogue: per-wave 16x68 LDS transpose, NO cross-wave barriers (fbuf wave-private;
  // final K-step's s_barrier already fenced the last slot reads)
  const int b = m0 >> 12, l0 = m0 & 4095;
  float* fbuf = (float*)smemc + w * 1088;
  const int fk = lane >> 4;
  #pragma unroll
  for (int j2 = 0; j2 < 4; ++j2) {
    #pragma unroll
    for (int i = 0; i < 4; ++i)
      *(f32x4*)&fbuf[fm * 68 + i * 16 + fk * 4] = acc[i][j2];
    lds_fence();
    #pragma unroll
    for (int p = 0; p < 4; ++p) {
      int nl = p * 4 + fk;
      int c = n0 + wn64 + j2 * 16 + nl;
      float4 v = *(float4*)&fbuf[nl * 68 + fm * 4];
      float bb = bias[c];
      ushort4 o;
      o.x = f2bf(v.x + bb); o.y = f2bf(v.y + bb);
      o.z = f2bf(v.z + bb); o.w = f2bf(v.w + bb);
      *(ushort4*)&proj[((size_t)b * C3 + c) * L_SEQ + l0 + wmRow + fm * 4] = o;
    }
    lds_fence();   // WAR: reads done before next j2 overwrites
  }
}

// ---------------- GEMM2: 128x128 tile, BK=32, ring-3 16KB (r4-proven, 768 blocks) ----------------
__device__ __forceinline__ void g_vmwait(int VM) {
  if (VM == 4)      asm volatile("s_waitcnt vmcnt(4)" ::: "memory");
  else if (VM == 0) asm volatile("s_waitcnt vmcnt(0)" ::: "memory");
}

template<bool STG, int VM>
__device__ __forceinline__ void g_step(int scur, int sstg, int kt, char* smemc, int tid,
                                       int wm64, int wn64, int fm, int csel,
                                       const unsigned short* aP, const unsigned short* bP,
                                       f32x4 (&acc)[4][4]) {
  const unsigned short* As = (const unsigned short*)(smemc + scur * 16384);
  const unsigned short* Bs = (const unsigned short*)(smemc + scur * 16384 + 8192);
  bf16x8 af[4], bfr[4];
  #pragma unroll
  for (int i = 0; i < 4; ++i) af[i]  = *(const bf16x8*)&As[(wm64 + i * 16 + fm) * 32 + csel];
  #pragma unroll
  for (int jj = 0; jj < 4; ++jj) bfr[jj] = *(const bf16x8*)&Bs[(wn64 + jj * 16 + fm) * 32 + csel];
  if (STG) {
    const unsigned short* ap = aP + (kt + 2) * 32;
    const unsigned short* bp = bP + (kt + 2) * 32;
    char* d = smemc + sstg * 16384 + tid * 16;
    gld_lds16(ap,         d);
    gld_lds16(ap + 49152, d + 4096);
    gld_lds16(bp,         d + 8192);
    gld_lds16(bp + 49152, d + 12288);
  }
  asm volatile("" ::: "memory");
  __builtin_amdgcn_s_barrier();
  __builtin_amdgcn_s_setprio(1);
  __builtin_amdgcn_sched_barrier(0);
  #pragma unroll
  for (int i = 0; i < 4; ++i)
    #pragma unroll
    for (int jj = 0; jj < 4; ++jj)
      acc[i][jj] = __builtin_amdgcn_mfma_f32_16x16x32_bf16(af[i], bfr[jj], acc[i][jj], 0, 0, 0);
  __builtin_amdgcn_sched_barrier(0);
  __builtin_amdgcn_s_setprio(0);
  g_vmwait(VM);
  asm volatile("" ::: "memory");
  __builtin_amdgcn_s_barrier();
}

__global__ __launch_bounds__(256, 3) void gemm2_k3(const unsigned short* __restrict__ A,
                                                   const unsigned short* __restrict__ Bt,
                                                   const float* __restrict__ bias,
                                                   float* __restrict__ out) {
  extern __shared__ char smemc[];          // 49152 B dynamic
  const int tid = threadIdx.x;
  const int w = tid >> 6, lane = tid & 63;
  const int id = blockIdx.x;               // 768 blocks = 3/CU x 256 CU, single round
  const int x8 = id & 7, jb = id >> 3;
  const int mt = x8 * 16 + jb / 6, nt = jb % 6;
  const int m0 = mt * 128, n0 = nt * 128;
  const int wm64 = (w & 1) * 64, wn64 = (w >> 1) * 64;
  const int fm = lane & 15;
  const int csel = (((lane >> 4) ^ ((fm >> 1) & 3)) << 3);
  const int q_src = ((tid & 3) ^ ((tid >> 3) & 3)) * 8;
  const unsigned short* aP = A  + (size_t)(m0 + (tid >> 2)) * 768 + q_src;
  const unsigned short* bP = Bt + (size_t)(n0 + (tid >> 2)) * 768 + q_src;
  f32x4 acc[4][4] = {};

  #pragma unroll
  for (int kt = 0; kt < 2; ++kt) {
    char* d = smemc + kt * 16384 + tid * 16;
    const unsigned short* ap = aP + kt * 32;
    const unsigned short* bp = bP + kt * 32;
    gld_lds16(ap,         d);
    gld_lds16(ap + 49152, d + 4096);
    gld_lds16(bp,         d + 8192);
    gld_lds16(bp + 49152, d + 12288);
  }
  asm volatile("s_waitcnt vmcnt(4)" ::: "memory");
  asm volatile("" ::: "memory");
  __builtin_amdgcn_s_barrier();
  int scur = 0;
  #pragma unroll 1
  for (int kt = 0; kt < 22; ++kt) {
    int sstg = scur + 2; if (sstg >= 3) sstg -= 3;
    g_step<true, 4>(scur, sstg, kt, smemc, tid, wm64, wn64, fm, csel, aP, bP, acc);
    scur = (scur == 2) ? 0 : scur + 1;
  }
  {
    int sstg = scur + 2; if (sstg >= 3) sstg -= 3;
    g_step<false, 0>(scur, sstg, 22, smemc, tid, wm64, wn64, fm, csel, aP, bP, acc);
    scur = (scur == 2) ? 0 : scur + 1;
  }
  g_step<false, -1>(scur, 0, 23, smemc, tid, wm64, wn64, fm, csel, aP, bP, acc);

  // epilogue: per-wave fbuf, lds_fence instead of barriers (wave-private;
  // slot2/fbuf overlap fenced by final K-step's s_barrier)
  float* fbuf = (float*)smemc + w * 1088;
  const int fk = lane >> 4;
  const int nf = lane & 15, mq = lane >> 4;
  float4 bb4 = *(const float4*)&bias[n0 + wn64 + nf * 4];
  #pragma unroll
  for (int i = 0; i < 4; ++i) {
    #pragma unroll
    for (int cg = 0; cg < 4; ++cg)
      #pragma unroll
      for (int r = 0; r < 4; ++r)
        fbuf[(fk * 4 + r) * 68 + cg * 16 + fm] = acc[i][cg][r];
    lds_fence();
    #pragma unroll
    for (int pass = 0; pass < 4; ++pass) {
      int m_l = pass * 4 + mq;
      float4 v = *(float4*)&fbuf[m_l * 68 + nf * 4];
      v.x += bb4.x; v.y += bb4.y; v.z += bb4.z; v.w += bb4.w;
      *(float4*)&out[(size_t)(m0 + wm64 + i * 16 + m_l) * D_DIM + n0 + wn64 + nf * 4] = v;
    }
    lds_fence();
  }
}

// ---------------- row kernel: conflict-free column LDS + shfl scan ----------------
__global__ __launch_bounds__(256) void row_kernel(const unsigned short* __restrict__ proj,
                                                  unsigned short* __restrict__ v2T,
                                                  const float* __restrict__ conv_k,
                                                  const float* __restrict__ conv_b,
                                                  const float* __restrict__ g_tab,
                                                  const float* __restrict__ f_bias) {
  __shared__ float buf0[4128];
  __shared__ float buf1[4128];
  __shared__ float sgs[2 * TAPS];
  __shared__ float wsum[4];
  __shared__ float bnd[3][4][2];
  const int tid = threadIdx.x;
  const int lane = tid & 63, w = tid >> 6;
  const int b = blockIdx.x / D_DIM, d = blockIdx.x % D_DIM;
  const int g = tid * 16;

  const unsigned short* rowV  = proj + ((size_t)b * C3 + 2 * D_DIM + d) * L_SEQ;
  const unsigned short* rowX0 = proj + ((size_t)b * C3 + d) * L_SEQ;
  const unsigned short* rowX1 = proj + ((size_t)b * C3 + D_DIM + d) * L_SEQ;

  float v[16], x0[16], x1[16];
  #pragma unroll
  for (int k = 0; k < 4; ++k) {
    ushort4 qv = *(const ushort4*)&rowV[g + k * 4];
    v[k * 4] = bf2f(qv.x); v[k * 4 + 1] = bf2f(qv.y); v[k * 4 + 2] = bf2f(qv.z); v[k * 4 + 3] = bf2f(qv.w);
    ushort4 q0 = *(const ushort4*)&rowX0[g + k * 4];
    x0[k * 4] = bf2f(q0.x); x0[k * 4 + 1] = bf2f(q0.y); x0[k * 4 + 2] = bf2f(q0.z); x0[k * 4 + 3] = bf2f(q0.w);
    ushort4 q1 = *(const ushort4*)&rowX1[g + k * 4];
    x1[k * 4] = bf2f(q1.x); x1[k * 4 + 1] = bf2f(q1.y); x1[k * 4 + 2] = bf2f(q1.z); x1[k * 4 + 3] = bf2f(q1.w);
  }

  if (tid < 32) {
    int ph = (tid & 15) * 258 + (tid >> 4);
    buf0[ph] = 0.f; buf1[ph] = 0.f;
  }
  if (tid < 64) sgs[tid] = g_tab[((size_t)((tid >> 5) * D_DIM + d)) * TAPS + (tid & 31)];
  if (lane == 63) {
    bnd[0][w][0] = v[14];  bnd[0][w][1] = v[15];
    bnd[1][w][0] = x0[14]; bnd[1][w][1] = x0[15];
    bnd[2][w][0] = x1[14]; bnd[2][w][1] = x1[15];
  }
  const int cv = 2 * D_DIM + d, cx0 = d, cx1 = D_DIM + d;
  const float kv0 = conv_k[cv],  kv1 = conv_k[C3 + cv],  kv2 = conv_k[2 * C3 + cv],  bv = conv_b[cv];
  const float ka0 = conv_k[cx0], ka1 = conv_k[C3 + cx0], ka2 = conv_k[2 * C3 + cx0], ba = conv_b[cx0];
  const float kb0 = conv_k[cx1], kb1 = conv_k[C3 + cx1], kb2 = conv_k[2 * C3 + cx1], bb = conv_b[cx1];
  const float fb0 = f_bias[d], fb1 = f_bias[D_DIM + d];
  __syncthreads();                                         // bar1

  float vm1 = __shfl_up(v[15], 1),  vm2 = __shfl_up(v[14], 1);
  float am1 = __shfl_up(x0[15], 1), am2 = __shfl_up(x0[14], 1);
  float bm1 = __shfl_up(x1[15], 1), bm2 = __shfl_up(x1[14], 1);
  if (lane == 0) {
    if (w > 0) {
      vm2 = bnd[0][w-1][0]; vm1 = bnd[0][w-1][1];
      am2 = bnd[1][w-1][0]; am1 = bnd[1][w-1][1];
      bm2 = bnd[2][w-1][0]; bm1 = bnd[2][w-1][1];
    } else {
      vm1 = vm2 = am1 = am2 = bm1 = bm2 = 0.f;
    }
  }
  float r[16];
  r[0] = vm2 * kv0 + vm1 * kv1 + v[0] * kv2 + bv;
  r[1] = vm1 * kv0 + v[0] * kv1 + v[1] * kv2 + bv;
  #pragma unroll
  for (int i = 2; i < 16; ++i) r[i] = v[i-2] * kv0 + v[i-1] * kv1 + v[i] * kv2 + bv;
  {
    float t0 = am2 * ka0 + am1 * ka1 + x0[0] * ka2 + ba;
    float t1 = am1 * ka0 + x0[0] * ka1 + x0[1] * ka2 + ba;
    #pragma unroll
    for (int i = 15; i >= 2; --i) x0[i] = x0[i-2] * ka0 + x0[i-1] * ka1 + x0[i] * ka2 + ba;
    x0[0] = t0; x0[1] = t1;
  }
  {
    float t0 = bm2 * kb0 + bm1 * kb1 + x1[0] * kb2 + bb;
    float t1 = bm1 * kb0 + x1[0] * kb1 + x1[1] * kb2 + bb;
    #pragma unroll
    for (int i = 15; i >= 2; --i) x1[i] = x1[i-2] * kb0 + x1[i-1] * kb1 + x1[i] * kb2 + bb;
    x1[0] = t0; x1[1] = t1;
  }
  #pragma unroll
  for (int i = 0; i < 16; ++i) buf0[i * 258 + tid + 2] = r[i];
  __syncthreads();                                         // bar2

  // ---- order 0 ----
  float h[32];
  #pragma unroll
  for (int j = 0; j < 32; ++j) h[j] = buf0[(j & 15) * 258 + tid + (j >> 4)];
  float p[16], run = 0.f;
  #pragma unroll
  for (int i = 0; i < 16; ++i) { run += r[i]; p[i] = run; }
  float s = run;
  #pragma unroll
  for (int off = 1; off < 64; off <<= 1) {
    float o = __shfl_up(s, off);
    if (lane >= off) s += o;
  }
  if (lane == 63) wsum[w] = s;
  __syncthreads();                                         // bar3
  float woff = 0.f;
  #pragma unroll
  for (int k = 0; k < 4; ++k) if (k < w) woff += wsum[k];
  float excl = woff + s - run;
  float y0[16];
  #pragma unroll
  for (int i = 0; i < 16; ++i) {
    float a = fb0 * (excl + p[i]);
    #pragma unroll
    for (int t = 0; t < TAPS; ++t) {
      float vv = (t <= i) ? r[i - t] : h[32 + i - t];
      a += sgs[t] * vv;
    }
    y0[i] = a * x0[i];
  }
  #pragma unroll
  for (int i = 0; i < 16; ++i) buf1[i * 258 + tid + 2] = y0[i];
  __syncthreads();                                         // bar4

  // ---- order 1 ----
  #pragma unroll
  for (int j = 0; j < 32; ++j) h[j] = buf1[(j & 15) * 258 + tid + (j >> 4)];
  run = 0.f;
  #pragma unroll
  for (int i = 0; i < 16; ++i) { run += y0[i]; p[i] = run; }
  s = run;
  #pragma unroll
  for (int off = 1; off < 64; off <<= 1) {
    float o = __shfl_up(s, off);
    if (lane >= off) s += o;
  }
  if (lane == 63) wsum[w] = s;
  __syncthreads();                                         // bar5
  woff = 0.f;
  #pragma unroll
  for (int k = 0; k < 4; ++k) if (k < w) woff += wsum[k];
  excl = woff + s - run;
  unsigned short yout[16];
  #pragma unroll
  for (int i = 0; i < 16; ++i) {
    float a = fb1 * (excl + p[i]);
    #pragma unroll
    for (int t = 0; t < TAPS; ++t) {
      float vv = (t <= i) ? y0[i - t] : h[32 + i - t];
      a += sgs[TAPS + t] * vv;
    }
    yout[i] = f2bf(a * x1[i]);
  }
  unsigned short* outRow = v2T + ((size_t)b * D_DIM + d) * L_SEQ + g;
  *(ushort4*)&outRow[0]  = *(ushort4*)&yout[0];
  *(ushort4*)&outRow[4]  = *(ushort4*)&yout[4];
  *(ushort4*)&outRow[8]  = *(ushort4*)&yout[8];
  *(ushort4*)&outRow[12] = *(ushort4*)&yout[12];
}

// ---------------- v2 transpose: bf16 [b][d][l] -> bf16 [b*l][d] ----------------
__global__ __launch_bounds__(256) void transpose_v2(const unsigned short* __restrict__ src,
                                                    unsigned short* __restrict__ dst) {
  __shared__ unsigned short t[64][66];
  const int l0 = blockIdx.x * 64, d0 = blockIdx.y * 64, b = blockIdx.z;
  const int tx = threadIdx.x & 31, ty = threadIdx.x >> 5;
  const unsigned short* s = src + ((size_t)b * D_DIM + d0) * L_SEQ + l0;
  #pragma unroll
  for (int r = 0; r < 8; ++r) {
    int dd = ty + r * 8;
    *(ushort2*)&t[dd][tx * 2] = *(const ushort2*)&s[(size_t)dd * L_SEQ + tx * 2];
  }
  __syncthreads();
  unsigned short* q = dst + ((size_t)b * L_SEQ + l0) * D_DIM + d0;
  #pragma unroll
  for (int r = 0; r < 8; ++r) {
    int ll = ty + r * 8;
    ushort2 v; v.x = t[tx * 2][ll]; v.y = t[tx * 2 + 1][ll];
    *(ushort2*)&q[(size_t)ll * D_DIM + tx * 2] = v;
  }
}

extern "C" void kernel_launch(void* const* d_in, const int* in_sizes, int n_in,
                              void* d_out, int out_size, void* d_ws, size_t ws_size,
                              hipStream_t stream) {
  (void)in_sizes; (void)n_in; (void)out_size; (void)ws_size;
  const float* u       = (const float*)d_in[0];
  const float* W_in    = (const float*)d_in[1];
  const float* b_in    = (const float*)d_in[2];
  const float* conv_k  = (const float*)d_in[3];
  const float* conv_b  = (const float*)d_in[4];
  const float* W1      = (const float*)d_in[5];
  const float* b1      = (const float*)d_in[6];
  const float* W2      = (const float*)d_in[7];
  const float* b2      = (const float*)d_in[8];
  const float* f_bias  = (const float*)d_in[9];
  const float* f_decay = (const float*)d_in[10];
  const float* W_out   = (const float*)d_in[11];
  const float* b_out   = (const float*)d_in[12];
  float* out = (float*)d_out;

  unsigned short* proj  = (unsigned short*)d_ws;                 // 4*2304*4096 bf16
  unsigned short* v2T   = proj + (size_t)4 * C3 * L_SEQ;         // 4*768*4096 bf16
  unsigned short* ubf   = v2T + (size_t)4 * D_DIM * L_SEQ;       // 16384*768 bf16
  unsigned short* v2F   = ubf;                                   // alias (dead after gemm1)
  unsigned short* W_inT = ubf + (size_t)16384 * 768;
  unsigned short* W_outT= W_inT + (size_t)C3 * D_DIM;
  float* g_tab          = (float*)(W_outT + (size_t)D_DIM * D_DIM);

  static bool g_attr = false;
  if (!g_attr) {
    (void)hipFuncSetAttribute(reinterpret_cast<const void*>(gemm1_2ph),
                              hipFuncAttributeMaxDynamicSharedMemorySize, 73728);
    (void)hipFuncSetAttribute(reinterpret_cast<const void*>(gemm2_k3),
                              hipFuncAttributeMaxDynamicSharedMemorySize, 49152);
    g_attr = true;
  }

  prep_kernel<<<14784, 256, 0, stream>>>(u, ubf, W_in, W_inT, W_out, W_outT,
                                         W1, b1, W2, b2, f_decay, g_tab);
  gemm1_2ph<<<1152, 512, 73728, stream>>>(ubf, W_inT, b_in, proj);
  row_kernel<<<3072, 256, 0, stream>>>(proj, v2T, conv_k, conv_b, g_tab, f_bias);
  transpose_v2<<<dim3(64, 12, 4), 256, 0, stream>>>(v2T, v2F);
  gemm2_k3<<<768, 256, 49152, stream>>>(v2F, W_outT, b_out, out);
}

// Round 6
// 257.498 us; speedup vs baseline: 1.1361x; 1.1361x over previous
//
#include <hip/hip_runtime.h>
#include <math.h>

#define L_SEQ 4096
#define D_DIM 768
#define C3    2304
#define TAPS  32

typedef __attribute__((ext_vector_type(8))) short bf16x8;
typedef __attribute__((ext_vector_type(4))) float f32x4;

__device__ __forceinline__ unsigned short f2bf(float x) {
  union { float f; unsigned u; } v; v.f = x;
  unsigned r = v.u + 0x7FFF + ((v.u >> 16) & 1);
  return (unsigned short)(r >> 16);
}
__device__ __forceinline__ float bf2f(unsigned short u) {
  union { unsigned u; float f; } v; v.u = ((unsigned)u) << 16; return v.f;
}
__device__ __forceinline__ void gld_lds16(const void* g, void* l) {
  __builtin_amdgcn_global_load_lds((const __attribute__((address_space(1))) void*)g,
                                   (__attribute__((address_space(3))) void*)l, 16, 0, 0);
}
// per-wave LDS fence (fbuf is wave-private scratch: no cross-wave barrier needed;
// DS ops are wave-FIFO, lgkmcnt(0)+sched_barrier prevents compiler reordering — rule #18)
__device__ __forceinline__ void lds_fence() {
  asm volatile("s_waitcnt lgkmcnt(0)" ::: "memory");
  __builtin_amdgcn_sched_barrier(0);
}

// ---------------- prep: fused filt + cvt + wtrans ----------------
// r5 post-mortem: filt branch recomputed sinf inside the K=33 dot (67584 sinf/block x192
// blocks -> ~60us serial tail, prep=78us). Fix: hoist pe[t][e]=sinf(tt*e*10) (1056 sinf,
// cooperative), then phi via FMA dot + 1 sinf, stored TRANSPOSED (stride 33) so stage-2
// reads are bank-conflict-free. Sin count/block: 69632 -> 3104. Same expressions/order.
// blocks [0,192): filt ; [192,12480): cvt ; [12480,14784): wtrans
__global__ __launch_bounds__(256) void prep_kernel(const float* __restrict__ u,
                                                   unsigned short* __restrict__ ubf,
                                                   const float* __restrict__ W_in,
                                                   unsigned short* __restrict__ W_inT,
                                                   const float* __restrict__ W_out,
                                                   unsigned short* __restrict__ W_outT,
                                                   const float* __restrict__ W1,
                                                   const float* __restrict__ b1,
                                                   const float* __restrict__ W2,
                                                   const float* __restrict__ b2,
                                                   const float* __restrict__ f_decay,
                                                   float* __restrict__ g_tab) {
  __shared__ float sh[3168];               // filt: pe[1056] + phiT[2112]; wtrans: 32x33
  const int bid = blockIdx.x;
  const int tid = threadIdx.x;
  if (bid < 192) {
    // ---- filt: g_tab[c2][t] for t<32 ----
    float* pe_s  = sh;                     // [t][e] t<32, e<33
    float* phiT  = sh + 1056;              // [f][t] f<64, t<32, stride 33
    for (int i = tid; i < 1056; i += 256) {
      int t = i / 33, e = i - t * 33;
      float tt = (float)t / 4095.0f;
      pe_s[i] = sinf(tt * (float)e * 10.0f);
    }
    __syncthreads();
    #pragma unroll
    for (int it = 0; it < 8; ++it) {
      int idx = tid + it * 256;
      int t = idx >> 6, f = idx & 63;
      float s = b1[f];
      #pragma unroll
      for (int e = 0; e < 33; ++e)
        s += pe_s[t * 33 + e] * W1[e * 64 + f];
      phiT[f * 33 + t] = sinf(10.0f * s);
    }
    __syncthreads();
    int idx = bid * 256 + tid;             // 1536*32 outputs
    int c2 = idx >> 5, t = idx & 31;
    float acc = b2[c2];
    #pragma unroll 8
    for (int f = 0; f < 64; ++f)
      acc += phiT[f * 33 + t] * W2[f * 1536 + c2];
    float r = expf(f_decay[c2]);
    g_tab[idx] = acc * expf(-r * (float)t * (4096.0f / 4095.0f));
  } else if (bid < 12480) {
    // ---- cvt u: fp32 -> bf16 ----
    int idx = ((bid - 192) * 256 + tid) * 4;
    float4 v = *(const float4*)&u[idx];
    ushort4 o;
    o.x = f2bf(v.x); o.y = f2bf(v.y); o.z = f2bf(v.z); o.w = f2bf(v.w);
    *(ushort4*)&ubf[idx] = o;
  } else {
    // ---- wtrans: fp32 [768][C] -> bf16 [C][768] ----
    float (*t)[33] = (float(*)[33])sh;
    int id = bid - 12480;
    const int z = (id >= 1728) ? 1 : 0;
    if (z) id -= 1728;
    const int nx = z ? 24 : 72;
    const int bx = id % nx, by = id / nx;
    const float* src = z ? W_out : W_in;
    unsigned short* dst = z ? W_outT : W_inT;
    const int C = z ? 768 : 2304;
    const int c0 = bx * 32, r0 = by * 32;
    const int tx = tid & 31, ty = tid >> 5;
    #pragma unroll
    for (int rr = 0; rr < 4; ++rr)
      t[ty + rr * 8][tx] = src[(long)(r0 + ty + rr * 8) * C + c0 + tx];
    __syncthreads();
    #pragma unroll
    for (int rr = 0; rr < 4; ++rr)
      dst[(long)(c0 + ty + rr * 8) * 768 + r0 + tx] = f2bf(t[tx][ty + rr * 8]);
  }
}

// ---------------- GEMM1: 256x128 tile, BK=32, ring-3 24KB (2 blk = 16 waves/CU) ----------------
__device__ __forceinline__ void g1_vmwait(int VM) {
  if (VM == 3)      asm volatile("s_waitcnt vmcnt(3)" ::: "memory");
  else if (VM == 0) asm volatile("s_waitcnt vmcnt(0)" ::: "memory");
}

template<bool STG, int VM>
__device__ __forceinline__ void g1_step(int scur, int sstg, int kt, char* smemc, int tid,
                                        int wmRow, int wn64, int fm, int csel,
                                        const unsigned short* aP, const unsigned short* bP,
                                        f32x4 (&acc)[4][4]) {
  const unsigned short* As = (const unsigned short*)(smemc + scur * 24576);
  const unsigned short* Bs = (const unsigned short*)(smemc + scur * 24576 + 16384);
  bf16x8 af[4], bfr[4];
  #pragma unroll
  for (int i = 0; i < 4; ++i) af[i]  = *(const bf16x8*)&As[(wmRow + i * 16 + fm) * 32 + csel];
  #pragma unroll
  for (int jj = 0; jj < 4; ++jj) bfr[jj] = *(const bf16x8*)&Bs[(wn64 + jj * 16 + fm) * 32 + csel];
  if (STG) {
    const unsigned short* ap = aP + (kt + 2) * 32;
    const unsigned short* bp = bP + (kt + 2) * 32;
    char* d = smemc + sstg * 24576 + tid * 16;
    gld_lds16(ap,         d);
    gld_lds16(ap + 98304, d + 8192);   // A rows 128..255
    gld_lds16(bp,         d + 16384);  // B rows 0..127
  }
  asm volatile("" ::: "memory");
  __builtin_amdgcn_s_barrier();
  __builtin_amdgcn_s_setprio(1);
  __builtin_amdgcn_sched_barrier(0);
  #pragma unroll
  for (int i = 0; i < 4; ++i)
    #pragma unroll
    for (int jj = 0; jj < 4; ++jj)
      acc[i][jj] = __builtin_amdgcn_mfma_f32_16x16x32_bf16(af[i], bfr[jj], acc[i][jj], 0, 0, 0);
  __builtin_amdgcn_sched_barrier(0);
  __builtin_amdgcn_s_setprio(0);
  g1_vmwait(VM);
  asm volatile("" ::: "memory");
  __builtin_amdgcn_s_barrier();
}

__global__ __launch_bounds__(512, 4) void gemm1_2ph(const unsigned short* __restrict__ A,
                                                    const unsigned short* __restrict__ Bt,
                                                    const float* __restrict__ bias,
                                                    unsigned short* __restrict__ proj) {
  extern __shared__ char smemc[];          // 73728 B dynamic (3 x 24576)
  const int tid = threadIdx.x;
  const int w = tid >> 6, lane = tid & 63;
  const int id = blockIdx.x;
  const int x8 = id & 7, jb = id >> 3;            // 1152 blocks, bijective XCD swizzle
  const int mt = x8 * 8 + jb / 18, nt = jb % 18;
  const int m0 = mt * 256, n0 = nt * 128;
  const int wmRow = (w & 3) * 64, wn64 = (w >> 2) * 64;
  const int fm = lane & 15;
  const int csel = (((lane >> 4) ^ ((fm >> 1) & 3)) << 3);
  const int q_src = ((tid & 3) ^ ((tid >> 3) & 3)) * 8;
  const unsigned short* aP = A  + (size_t)(m0 + (tid >> 2)) * 768 + q_src;
  const unsigned short* bP = Bt + (size_t)(n0 + (tid >> 2)) * 768 + q_src;
  f32x4 acc[4][4] = {};

  #pragma unroll
  for (int kt = 0; kt < 2; ++kt) {
    char* d = smemc + kt * 24576 + tid * 16;
    const unsigned short* ap = aP + kt * 32;
    const unsigned short* bp = bP + kt * 32;
    gld_lds16(ap,         d);
    gld_lds16(ap + 98304, d + 8192);
    gld_lds16(bp,         d + 16384);
  }
  asm volatile("s_waitcnt vmcnt(3)" ::: "memory");
  asm volatile("" ::: "memory");
  __builtin_amdgcn_s_barrier();

  int scur = 0;
  #pragma unroll 1
  for (int kt = 0; kt < 22; ++kt) {
    int sstg = scur + 2; if (sstg >= 3) sstg -= 3;
    g1_step<true, 3>(scur, sstg, kt, smemc, tid, wmRow, wn64, fm, csel, aP, bP, acc);
    scur = (scur == 2) ? 0 : scur + 1;
  }
  {
    int sstg = scur + 2; if (sstg >= 3) sstg -= 3;
    g1_step<false, 0>(scur, sstg, 22, smemc, tid, wmRow, wn64, fm, csel, aP, bP, acc);
    scur = (scur == 2) ? 0 : scur + 1;
  }
  g1_step<false, -1>(scur, 0, 23, smemc, tid, wmRow, wn64, fm, csel, aP, bP, acc);

  // epilogue: per-wave 16x68 LDS transpose, per-wave fences (fbuf wave-private)
  const int b = m0 >> 12, l0 = m0 & 4095;
  float* fbuf = (float*)smemc + w * 1088;
  const int fk = lane >> 4;
  #pragma unroll
  for (int j2 = 0; j2 < 4; ++j2) {
    #pragma unroll
    for (int i = 0; i < 4; ++i)
      *(f32x4*)&fbuf[fm * 68 + i * 16 + fk * 4] = acc[i][j2];
    lds_fence();
    #pragma unroll
    for (int p = 0; p < 4; ++p) {
      int nl = p * 4 + fk;
      int c = n0 + wn64 + j2 * 16 + nl;
      float4 v = *(float4*)&fbuf[nl * 68 + fm * 4];
      float bb = bias[c];
      ushort4 o;
      o.x = f2bf(v.x + bb); o.y = f2bf(v.y + bb);
      o.z = f2bf(v.z + bb); o.w = f2bf(v.w + bb);
      *(ushort4*)&proj[((size_t)b * C3 + c) * L_SEQ + l0 + wmRow + fm * 4] = o;
    }
    lds_fence();   // WAR: reads done before next j2 overwrites
  }
}

// ---------------- GEMM2: 128x128 tile, BK=32, ring-3 16KB (768 blocks = 3/CU) ----------------
__device__ __forceinline__ void g_vmwait(int VM) {
  if (VM == 4)      asm volatile("s_waitcnt vmcnt(4)" ::: "memory");
  else if (VM == 0) asm volatile("s_waitcnt vmcnt(0)" ::: "memory");
}

template<bool STG, int VM>
__device__ __forceinline__ void g_step(int scur, int sstg, int kt, char* smemc, int tid,
                                       int wm64, int wn64, int fm, int csel,
                                       const unsigned short* aP, const unsigned short* bP,
                                       f32x4 (&acc)[4][4]) {
  const unsigned short* As = (const unsigned short*)(smemc + scur * 16384);
  const unsigned short* Bs = (const unsigned short*)(smemc + scur * 16384 + 8192);
  bf16x8 af[4], bfr[4];
  #pragma unroll
  for (int i = 0; i < 4; ++i) af[i]  = *(const bf16x8*)&As[(wm64 + i * 16 + fm) * 32 + csel];
  #pragma unroll
  for (int jj = 0; jj < 4; ++jj) bfr[jj] = *(const bf16x8*)&Bs[(wn64 + jj * 16 + fm) * 32 + csel];
  if (STG) {
    const unsigned short* ap = aP + (kt + 2) * 32;
    const unsigned short* bp = bP + (kt + 2) * 32;
    char* d = smemc + sstg * 16384 + tid * 16;
    gld_lds16(ap,         d);
    gld_lds16(ap + 49152, d + 4096);
    gld_lds16(bp,         d + 8192);
    gld_lds16(bp + 49152, d + 12288);
  }
  asm volatile("" ::: "memory");
  __builtin_amdgcn_s_barrier();
  __builtin_amdgcn_s_setprio(1);
  __builtin_amdgcn_sched_barrier(0);
  #pragma unroll
  for (int i = 0; i < 4; ++i)
    #pragma unroll
    for (int jj = 0; jj < 4; ++jj)
      acc[i][jj] = __builtin_amdgcn_mfma_f32_16x16x32_bf16(af[i], bfr[jj], acc[i][jj], 0, 0, 0);
  __builtin_amdgcn_sched_barrier(0);
  __builtin_amdgcn_s_setprio(0);
  g_vmwait(VM);
  asm volatile("" ::: "memory");
  __builtin_amdgcn_s_barrier();
}

__global__ __launch_bounds__(256, 3) void gemm2_k3(const unsigned short* __restrict__ A,
                                                   const unsigned short* __restrict__ Bt,
                                                   const float* __restrict__ bias,
                                                   float* __restrict__ out) {
  extern __shared__ char smemc[];          // 49152 B dynamic
  const int tid = threadIdx.x;
  const int w = tid >> 6, lane = tid & 63;
  const int id = blockIdx.x;               // 768 blocks = 3/CU x 256 CU, single round
  const int x8 = id & 7, jb = id >> 3;
  const int mt = x8 * 16 + jb / 6, nt = jb % 6;
  const int m0 = mt * 128, n0 = nt * 128;
  const int wm64 = (w & 1) * 64, wn64 = (w >> 1) * 64;
  const int fm = lane & 15;
  const int csel = (((lane >> 4) ^ ((fm >> 1) & 3)) << 3);
  const int q_src = ((tid & 3) ^ ((tid >> 3) & 3)) * 8;
  const unsigned short* aP = A  + (size_t)(m0 + (tid >> 2)) * 768 + q_src;
  const unsigned short* bP = Bt + (size_t)(n0 + (tid >> 2)) * 768 + q_src;
  f32x4 acc[4][4] = {};

  #pragma unroll
  for (int kt = 0; kt < 2; ++kt) {
    char* d = smemc + kt * 16384 + tid * 16;
    const unsigned short* ap = aP + kt * 32;
    const unsigned short* bp = bP + kt * 32;
    gld_lds16(ap,         d);
    gld_lds16(ap + 49152, d + 4096);
    gld_lds16(bp,         d + 8192);
    gld_lds16(bp + 49152, d + 12288);
  }
  asm volatile("s_waitcnt vmcnt(4)" ::: "memory");
  asm volatile("" ::: "memory");
  __builtin_amdgcn_s_barrier();
  int scur = 0;
  #pragma unroll 1
  for (int kt = 0; kt < 22; ++kt) {
    int sstg = scur + 2; if (sstg >= 3) sstg -= 3;
    g_step<true, 4>(scur, sstg, kt, smemc, tid, wm64, wn64, fm, csel, aP, bP, acc);
    scur = (scur == 2) ? 0 : scur + 1;
  }
  {
    int sstg = scur + 2; if (sstg >= 3) sstg -= 3;
    g_step<false, 0>(scur, sstg, 22, smemc, tid, wm64, wn64, fm, csel, aP, bP, acc);
    scur = (scur == 2) ? 0 : scur + 1;
  }
  g_step<false, -1>(scur, 0, 23, smemc, tid, wm64, wn64, fm, csel, aP, bP, acc);

  // epilogue: per-wave fbuf, per-wave fences
  float* fbuf = (float*)smemc + w * 1088;
  const int fk = lane >> 4;
  const int nf = lane & 15, mq = lane >> 4;
  float4 bb4 = *(const float4*)&bias[n0 + wn64 + nf * 4];
  #pragma unroll
  for (int i = 0; i < 4; ++i) {
    #pragma unroll
    for (int cg = 0; cg < 4; ++cg)
      #pragma unroll
      for (int r = 0; r < 4; ++r)
        fbuf[(fk * 4 + r) * 68 + cg * 16 + fm] = acc[i][cg][r];
    lds_fence();
    #pragma unroll
    for (int pass = 0; pass < 4; ++pass) {
      int m_l = pass * 4 + mq;
      float4 v = *(float4*)&fbuf[m_l * 68 + nf * 4];
      v.x += bb4.x; v.y += bb4.y; v.z += bb4.z; v.w += bb4.w;
      *(float4*)&out[(size_t)(m0 + wm64 + i * 16 + m_l) * D_DIM + n0 + wn64 + nf * 4] = v;
    }
    lds_fence();
  }
}

// ---------------- row kernel: conflict-free column LDS + shfl scan ----------------
__global__ __launch_bounds__(256) void row_kernel(const unsigned short* __restrict__ proj,
                                                  unsigned short* __restrict__ v2T,
                                                  const float* __restrict__ conv_k,
                                                  const float* __restrict__ conv_b,
                                                  const float* __restrict__ g_tab,
                                                  const float* __restrict__ f_bias) {
  __shared__ float buf0[4128];
  __shared__ float buf1[4128];
  __shared__ float sgs[2 * TAPS];
  __shared__ float wsum[4];
  __shared__ float bnd[3][4][2];
  const int tid = threadIdx.x;
  const int lane = tid & 63, w = tid >> 6;
  const int b = blockIdx.x / D_DIM, d = blockIdx.x % D_DIM;
  const int g = tid * 16;

  const unsigned short* rowV  = proj + ((size_t)b * C3 + 2 * D_DIM + d) * L_SEQ;
  const unsigned short* rowX0 = proj + ((size_t)b * C3 + d) * L_SEQ;
  const unsigned short* rowX1 = proj + ((size_t)b * C3 + D_DIM + d) * L_SEQ;

  float v[16], x0[16], x1[16];
  #pragma unroll
  for (int k = 0; k < 4; ++k) {
    ushort4 qv = *(const ushort4*)&rowV[g + k * 4];
    v[k * 4] = bf2f(qv.x); v[k * 4 + 1] = bf2f(qv.y); v[k * 4 + 2] = bf2f(qv.z); v[k * 4 + 3] = bf2f(qv.w);
    ushort4 q0 = *(const ushort4*)&rowX0[g + k * 4];
    x0[k * 4] = bf2f(q0.x); x0[k * 4 + 1] = bf2f(q0.y); x0[k * 4 + 2] = bf2f(q0.z); x0[k * 4 + 3] = bf2f(q0.w);
    ushort4 q1 = *(const ushort4*)&rowX1[g + k * 4];
    x1[k * 4] = bf2f(q1.x); x1[k * 4 + 1] = bf2f(q1.y); x1[k * 4 + 2] = bf2f(q1.z); x1[k * 4 + 3] = bf2f(q1.w);
  }

  if (tid < 32) {
    int ph = (tid & 15) * 258 + (tid >> 4);
    buf0[ph] = 0.f; buf1[ph] = 0.f;
  }
  if (tid < 64) sgs[tid] = g_tab[((size_t)((tid >> 5) * D_DIM + d)) * TAPS + (tid & 31)];
  if (lane == 63) {
    bnd[0][w][0] = v[14];  bnd[0][w][1] = v[15];
    bnd[1][w][0] = x0[14]; bnd[1][w][1] = x0[15];
    bnd[2][w][0] = x1[14]; bnd[2][w][1] = x1[15];
  }
  const int cv = 2 * D_DIM + d, cx0 = d, cx1 = D_DIM + d;
  const float kv0 = conv_k[cv],  kv1 = conv_k[C3 + cv],  kv2 = conv_k[2 * C3 + cv],  bv = conv_b[cv];
  const float ka0 = conv_k[cx0], ka1 = conv_k[C3 + cx0], ka2 = conv_k[2 * C3 + cx0], ba = conv_b[cx0];
  const float kb0 = conv_k[cx1], kb1 = conv_k[C3 + cx1], kb2 = conv_k[2 * C3 + cx1], bb = conv_b[cx1];
  const float fb0 = f_bias[d], fb1 = f_bias[D_DIM + d];
  __syncthreads();                                         // bar1

  float vm1 = __shfl_up(v[15], 1),  vm2 = __shfl_up(v[14], 1);
  float am1 = __shfl_up(x0[15], 1), am2 = __shfl_up(x0[14], 1);
  float bm1 = __shfl_up(x1[15], 1), bm2 = __shfl_up(x1[14], 1);
  if (lane == 0) {
    if (w > 0) {
      vm2 = bnd[0][w-1][0]; vm1 = bnd[0][w-1][1];
      am2 = bnd[1][w-1][0]; am1 = bnd[1][w-1][1];
      bm2 = bnd[2][w-1][0]; bm1 = bnd[2][w-1][1];
    } else {
      vm1 = vm2 = am1 = am2 = bm1 = bm2 = 0.f;
    }
  }
  float r[16];
  r[0] = vm2 * kv0 + vm1 * kv1 + v[0] * kv2 + bv;
  r[1] = vm1 * kv0 + v[0] * kv1 + v[1] * kv2 + bv;
  #pragma unroll
  for (int i = 2; i < 16; ++i) r[i] = v[i-2] * kv0 + v[i-1] * kv1 + v[i] * kv2 + bv;
  {
    float t0 = am2 * ka0 + am1 * ka1 + x0[0] * ka2 + ba;
    float t1 = am1 * ka0 + x0[0] * ka1 + x0[1] * ka2 + ba;
    #pragma unroll
    for (int i = 15; i >= 2; --i) x0[i] = x0[i-2] * ka0 + x0[i-1] * ka1 + x0[i] * ka2 + ba;
    x0[0] = t0; x0[1] = t1;
  }
  {
    float t0 = bm2 * kb0 + bm1 * kb1 + x1[0] * kb2 + bb;
    float t1 = bm1 * kb0 + x1[0] * kb1 + x1[1] * kb2 + bb;
    #pragma unroll
    for (int i = 15; i >= 2; --i) x1[i] = x1[i-2] * kb0 + x1[i-1] * kb1 + x1[i] * kb2 + bb;
    x1[0] = t0; x1[1] = t1;
  }
  #pragma unroll
  for (int i = 0; i < 16; ++i) buf0[i * 258 + tid + 2] = r[i];
  __syncthreads();                                         // bar2

  // ---- order 0 ----
  float h[32];
  #pragma unroll
  for (int j = 0; j < 32; ++j) h[j] = buf0[(j & 15) * 258 + tid + (j >> 4)];
  float p[16], run = 0.f;
  #pragma unroll
  for (int i = 0; i < 16; ++i) { run += r[i]; p[i] = run; }
  float s = run;
  #pragma unroll
  for (int off = 1; off < 64; off <<= 1) {
    float o = __shfl_up(s, off);
    if (lane >= off) s += o;
  }
  if (lane == 63) wsum[w] = s;
  __syncthreads();                                         // bar3
  float woff = 0.f;
  #pragma unroll
  for (int k = 0; k < 4; ++k) if (k < w) woff += wsum[k];
  float excl = woff + s - run;
  float y0[16];
  #pragma unroll
  for (int i = 0; i < 16; ++i) {
    float a = fb0 * (excl + p[i]);
    #pragma unroll
    for (int t = 0; t < TAPS; ++t) {
      float vv = (t <= i) ? r[i - t] : h[32 + i - t];
      a += sgs[t] * vv;
    }
    y0[i] = a * x0[i];
  }
  #pragma unroll
  for (int i = 0; i < 16; ++i) buf1[i * 258 + tid + 2] = y0[i];
  __syncthreads();                                         // bar4

  // ---- order 1 ----
  #pragma unroll
  for (int j = 0; j < 32; ++j) h[j] = buf1[(j & 15) * 258 + tid + (j >> 4)];
  run = 0.f;
  #pragma unroll
  for (int i = 0; i < 16; ++i) { run += y0[i]; p[i] = run; }
  s = run;
  #pragma unroll
  for (int off = 1; off < 64; off <<= 1) {
    float o = __shfl_up(s, off);
    if (lane >= off) s += o;
  }
  if (lane == 63) wsum[w] = s;
  __syncthreads();                                         // bar5
  woff = 0.f;
  #pragma unroll
  for (int k = 0; k < 4; ++k) if (k < w) woff += wsum[k];
  excl = woff + s - run;
  unsigned short yout[16];
  #pragma unroll
  for (int i = 0; i < 16; ++i) {
    float a = fb1 * (excl + p[i]);
    #pragma unroll
    for (int t = 0; t < TAPS; ++t) {
      float vv = (t <= i) ? y0[i - t] : h[32 + i - t];
      a += sgs[TAPS + t] * vv;
    }
    yout[i] = f2bf(a * x1[i]);
  }
  unsigned short* outRow = v2T + ((size_t)b * D_DIM + d) * L_SEQ + g;
  *(ushort4*)&outRow[0]  = *(ushort4*)&yout[0];
  *(ushort4*)&outRow[4]  = *(ushort4*)&yout[4];
  *(ushort4*)&outRow[8]  = *(ushort4*)&yout[8];
  *(ushort4*)&outRow[12] = *(ushort4*)&yout[12];
}

// ---------------- v2 transpose: bf16 [b][d][l] -> bf16 [b*l][d] ----------------
__global__ __launch_bounds__(256) void transpose_v2(const unsigned short* __restrict__ src,
                                                    unsigned short* __restrict__ dst) {
  __shared__ unsigned short t[64][66];
  const int l0 = blockIdx.x * 64, d0 = blockIdx.y * 64, b = blockIdx.z;
  const int tx = threadIdx.x & 31, ty = threadIdx.x >> 5;
  const unsigned short* s = src + ((size_t)b * D_DIM + d0) * L_SEQ + l0;
  #pragma unroll
  for (int r = 0; r < 8; ++r) {
    int dd = ty + r * 8;
    *(ushort2*)&t[dd][tx * 2] = *(const ushort2*)&s[(size_t)dd * L_SEQ + tx * 2];
  }
  __syncthreads();
  unsigned short* q = dst + ((size_t)b * L_SEQ + l0) * D_DIM + d0;
  #pragma unroll
  for (int r = 0; r < 8; ++r) {
    int ll = ty + r * 8;
    ushort2 v; v.x = t[tx * 2][ll]; v.y = t[tx * 2 + 1][ll];
    *(ushort2*)&q[(size_t)ll * D_DIM + tx * 2] = v;
  }
}

extern "C" void kernel_launch(void* const* d_in, const int* in_sizes, int n_in,
                              void* d_out, int out_size, void* d_ws, size_t ws_size,
                              hipStream_t stream) {
  (void)in_sizes; (void)n_in; (void)out_size; (void)ws_size;
  const float* u       = (const float*)d_in[0];
  const float* W_in    = (const float*)d_in[1];
  const float* b_in    = (const float*)d_in[2];
  const float* conv_k  = (const float*)d_in[3];
  const float* conv_b  = (const float*)d_in[4];
  const float* W1      = (const float*)d_in[5];
  const float* b1      = (const float*)d_in[6];
  const float* W2      = (const float*)d_in[7];
  const float* b2      = (const float*)d_in[8];
  const float* f_bias  = (const float*)d_in[9];
  const float* f_decay = (const float*)d_in[10];
  const float* W_out   = (const float*)d_in[11];
  const float* b_out   = (const float*)d_in[12];
  float* out = (float*)d_out;

  unsigned short* proj  = (unsigned short*)d_ws;                 // 4*2304*4096 bf16
  unsigned short* v2T   = proj + (size_t)4 * C3 * L_SEQ;         // 4*768*4096 bf16
  unsigned short* ubf   = v2T + (size_t)4 * D_DIM * L_SEQ;       // 16384*768 bf16
  unsigned short* v2F   = ubf;                                   // alias (dead after gemm1)
  unsigned short* W_inT = ubf + (size_t)16384 * 768;
  unsigned short* W_outT= W_inT + (size_t)C3 * D_DIM;
  float* g_tab          = (float*)(W_outT + (size_t)D_DIM * D_DIM);

  static bool g_attr = false;
  if (!g_attr) {
    (void)hipFuncSetAttribute(reinterpret_cast<const void*>(gemm1_2ph),
                              hipFuncAttributeMaxDynamicSharedMemorySize, 73728);
    (void)hipFuncSetAttribute(reinterpret_cast<const void*>(gemm2_k3),
                              hipFuncAttributeMaxDynamicSharedMemorySize, 49152);
    g_attr = true;
  }

  prep_kernel<<<14784, 256, 0, stream>>>(u, ubf, W_in, W_inT, W_out, W_outT,
                                         W1, b1, W2, b2, f_decay, g_tab);
  gemm1_2ph<<<1152, 512, 73728, stream>>>(ubf, W_inT, b_in, proj);
  row_kernel<<<3072, 256, 0, stream>>>(proj, v2T, conv_k, conv_b, g_tab, f_bias);
  transpose_v2<<<dim3(64, 12, 4), 256, 0, stream>>>(v2T, v2F);
  gemm2_k3<<<768, 256, 49152, stream>>>(v2F, W_outT, b_out, out);
}